// Round 6
// baseline (1315.767 us; speedup 1.0000x reference)
//
#include <hip/hip_runtime.h>
#include <hip/hip_bf16.h>

// out[i] = probs[X[i,0]*125000 + X[i,1]*2500 + X[i,2]*50 + X[i,3]]
//
// Rounds 1-5: single-pass pinned at 144.5us / FETCH 482 MB / 3.64 TB/s under
// every MLP/cache-policy variation. Decomposition: X 128 MB + out 32 MB +
// gather fills 354 MB, vs 184 MB per-XCD compulsory floor -> ~170 MB of L2
// CAPACITY misses (25 MB table >> 4 MB per-XCD L2). Round 3 proved idx-
// partitioned WRITES are fatal (283 MB partial lines) -> slice results must
// merge ON-CHIP before storing.
//
// Round 6 "convoy": all resident blocks sweep the 8 table slices (3.125 MB
// each, L2-resident) in lockstep; idx in LDS, val[] merged in registers,
// ONE dense store at the end. Lockstep via perf-only soft barrier in d_ws
// (bounded spin + timeout: correctness never depends on it — each thread's
// work is fully independent; worst case it just degrades to round-1 traffic).
// Residency: 2048 blocks x 256 thr, VPT=16 (= 8.39M slots >= 8M), 16 KB LDS
// -> 8 blocks/CU, __launch_bounds__(256,8) caps VGPR at 64.

typedef int v4i __attribute__((ext_vector_type(4)));

constexpr int BLOCK  = 256;
constexpr int VPT    = 16;
constexpr int TILE   = BLOCK * VPT;     // 4096 samples/block
constexpr int TABLE  = 6250000;
constexpr int NSLICE = 8;
constexpr int SLICE  = TABLE / NSLICE;  // 781250 exactly

__device__ __forceinline__ void soft_barrier(int* bar, int phase, int expect,
                                             long long timeout) {
    __syncthreads();
    if (threadIdx.x == 0) {
        atomicAdd(&bar[phase], 1);  // device scope by default (m20)
        long long t0 = clock64();
        while (__hip_atomic_load(&bar[phase], __ATOMIC_RELAXED,
                                 __HIP_MEMORY_SCOPE_AGENT) < expect) {
            __builtin_amdgcn_s_sleep(2);
            if (clock64() - t0 > timeout) break;  // perf-only: never deadlock
        }
    }
    __syncthreads();
}

__global__ __launch_bounds__(BLOCK, 8) void jc_convoy(
    const v4i* __restrict__ X, const float* __restrict__ probs,
    float* __restrict__ out, int* __restrict__ bar, int n, int nblocks)
{
    __shared__ int s_idx[TILE];  // 16 KB: keeps VGPRs <= 64 for 8 blocks/CU
    const int tid  = threadIdx.x;
    const int base = blockIdx.x * TILE + tid;

    // Phase 0: stream X, compute flat idx into LDS (lane-private, conflict-free).
    #pragma unroll
    for (int v = 0; v < VPT; ++v) {
        int i = base + v * BLOCK;
        i = i < n ? i : n - 1;                       // clamp tail (stores guarded)
        v4i x = __builtin_nontemporal_load(&X[i]);
        s_idx[tid + v * BLOCK] = x.x * 125000 + x.y * 2500 + x.z * 50 + x.w;
    }

    // Align the grid after the load phase (generous cap: dispatch ramp).
    soft_barrier(bar, 0, nblocks, 150000);

    // Phase 1: sweep table slices in lockstep; merge into registers.
    float val[VPT];
    #pragma unroll 1
    for (int s = 0; s < NSLICE; ++s) {
        const unsigned lo = (unsigned)(s * SLICE);
        #pragma unroll
        for (int v = 0; v < VPT; ++v) {
            int id = s_idx[tid + v * BLOCK];
            if ((unsigned)id - lo < (unsigned)SLICE)
                val[v] = probs[id];                  // L2-resident slice gather
        }
        if (s + 1 < NSLICE) soft_barrier(bar, s + 1, nblocks, 50000);
    }

    // Phase 2: ONE dense store per sample (the round-3 write-amp fix).
    #pragma unroll
    for (int v = 0; v < VPT; ++v) {
        int i = base + v * BLOCK;
        if (i < n) __builtin_nontemporal_store(val[v], &out[i]);
    }
}

// Fallback: round-1 kernel if workspace can't hold the barrier counters.
__global__ __launch_bounds__(256) void jc_simple(
    const v4i* __restrict__ X, const float* __restrict__ probs,
    float* __restrict__ out, int n)
{
    int i = blockIdx.x * blockDim.x + threadIdx.x;
    if (i < n) {
        v4i x = X[i];
        out[i] = probs[x.x * 125000 + x.y * 2500 + x.z * 50 + x.w];
    }
}

extern "C" void kernel_launch(void* const* d_in, const int* in_sizes, int n_in,
                              void* d_out, int out_size, void* d_ws, size_t ws_size,
                              hipStream_t stream) {
    const float* probs = (const float*)d_in[0];
    const v4i*   X     = (const v4i*)d_in[1];   // [N,4] int32 rows
    float* out = (float*)d_out;
    int n = out_size;  // 8,000,000

    if (ws_size < 256) {
        jc_simple<<<(n + 255) / 256, 256, 0, stream>>>(X, probs, out, n);
        return;
    }

    int* bar = (int*)d_ws;                       // NSLICE counters (phase 0..7)
    hipMemsetAsync(bar, 0, 256, stream);         // ws is 0xAA-poisoned each call

    int grid = (n + TILE - 1) / TILE;            // 1954 for n=8M... actually 8M/4096=1953.125 -> 1954
    jc_convoy<<<grid, BLOCK, 0, stream>>>(X, probs, out, bar, n, grid);
}